// Round 14
// baseline (82.327 us; speedup 1.0000x reference)
//
#include <hip/hip_runtime.h>

// 3D trilinear warp (grid_sample, align_corners=True equivalent, zeros padding)
// src:  [B=2, C=1, D=160, H=192, W=224] f32
// flow: [B=2, 3,   D,     H,     W    ] f32  (d,h,w voxel displacements)
// out:  [B=2, C=1, D,     H,     W    ] f32
//
// R14: T3/T4 two-brick pipeline. Block = TWO d-adjacent 16d x 8h x 16w bricks,
// double-buffered LDS (2 x 36.9 KB), global_load_lds DMA staging for both
// issued UP FRONT; counted s_waitcnt vmcnt(5) + raw s_barrier -> compute
// brick0 while brick1's DMA is still in flight; vmcnt(1) + barrier ->
// compute brick1. Hides stage latency + barrier drain behind compute
// (R11/R12/R13 lesson: staging WORK isn't the bound; the serialized
// stage->drain->compute critical path is).

#define DD 160
#define HH 192
#define WW 224
constexpr int DHW = DD * HH * WW;          // 6,881,280
constexpr int BLOCK = 512;
// Brick: 16d x 8h x 16w; block covers a d-pair (32d x 8h x 16w).
constexpr int QT = DD / 32;                // 5 d-pairs
constexpr int HT = HH / 8;                 // 24
constexpr int WT = WW / 16;                // 14
constexpr int PAIRS_PER_B = QT * HT * WT;  // 1680
constexpr int NWG = 2 * PAIRS_PER_B;       // 3360, divisible by 8
constexpr int NXCD = 8;
constexpr int CHUNK = NWG / NXCD;          // 420

// Staged region per brick: halo 4. d: 24; h: 16; w: 24 floats, stride 24
// (linear in LDS -> global_load_lds-compatible).
constexpr int RD = 24, RH = 16, RWE = 24, RWS = 24;
constexpr int TILE_N = RD * RH * RWS;      // 9216 floats = 36,864 B per buf
constexpr int SROWS = RD * RH;             // 384 rows
constexpr int SCHUNKS = SROWS * 6;         // 2304 float4 chunks
constexpr int WCHUNKS = SCHUNKS / 8;       // 288 chunks per wave
constexpr int DROW = RH * RWS;             // d-stride in floats (384)

typedef float vfloat4 __attribute__((ext_vector_type(4)));

// Global fallback tap (rare, beyond-halo): branchless, clamped, validity
// folded into weights — matches reference clip+valid semantics.
__device__ __forceinline__ float trilerp_global(const float* __restrict__ sbase,
                                                float cd, float ch, float cw) {
    float d0f = floorf(cd), h0f = floorf(ch), w0f = floorf(cw);
    float fd = cd - d0f, fh = ch - h0f, fw = cw - w0f;
    int d0 = (int)d0f, h0 = (int)h0f, w0 = (int)w0f;
    int d1 = d0 + 1, h1 = h0 + 1, w1 = w0 + 1;

    float wd0 = (1.0f - fd) * ((unsigned)d0 < (unsigned)DD ? 1.0f : 0.0f);
    float wd1 = fd          * ((unsigned)d1 < (unsigned)DD ? 1.0f : 0.0f);
    float wh0 = (1.0f - fh) * ((unsigned)h0 < (unsigned)HH ? 1.0f : 0.0f);
    float wh1 = fh          * ((unsigned)h1 < (unsigned)HH ? 1.0f : 0.0f);
    float ww0 = (1.0f - fw) * ((unsigned)w0 < (unsigned)WW ? 1.0f : 0.0f);
    float ww1 = fw          * ((unsigned)w1 < (unsigned)WW ? 1.0f : 0.0f);

    int d0c = min(max(d0, 0), DD - 1), d1c = min(max(d1, 0), DD - 1);
    int h0c = min(max(h0, 0), HH - 1), h1c = min(max(h1, 0), HH - 1);
    int w0c = min(max(w0, 0), WW - 1), w1c = min(max(w1, 0), WW - 1);

    const float* p00 = sbase + (d0c * HH + h0c) * WW;
    const float* p01 = sbase + (d0c * HH + h1c) * WW;
    const float* p10 = sbase + (d1c * HH + h0c) * WW;
    const float* p11 = sbase + (d1c * HH + h1c) * WW;

    return wd0 * (wh0 * (ww0 * p00[w0c] + ww1 * p00[w1c]) +
                  wh1 * (ww0 * p01[w0c] + ww1 * p01[w1c])) +
           wd1 * (wh0 * (ww0 * p10[w0c] + ww1 * p10[w1c]) +
                  wh1 * (ww0 * p11[w0c] + ww1 * p11[w1c]));
}

// Full per-brick evaluation from its LDS buffer (post-barrier).
__device__ __forceinline__ void compute_brick(
    const float* __restrict__ tb, const float* __restrict__ sbase,
    int dB4, int hB4, int wB4,
    const float* cdv, const float* chv, const float* cwv,
    bool interior, float* res) {
    float fdq[4], fhq[4], fwq[4];
    int base[4];
    bool allin = true;
    #pragma unroll
    for (int k = 0; k < 4; ++k) {
        float cd = cdv[k], ch = chv[k], cw = cwv[k];
        float d0f = floorf(cd), h0f = floorf(ch), w0f = floorf(cw);
        fdq[k] = cd - d0f; fhq[k] = ch - h0f; fwq[k] = cw - w0f;
        int rd = (int)d0f - dB4, rh = (int)h0f - hB4, rw = (int)w0f - wB4;
        allin = allin & ((unsigned)rd < (unsigned)(RD - 1)) &
                        ((unsigned)rh < (unsigned)(RH - 1)) &
                        ((unsigned)rw < (unsigned)(RWE - 1));
        base[k] = (rd * RH + rh) * RWS + rw;
    }
    if (allin) {
        if (interior) {
            // Mask-free: 8 LDS taps + 7-lerp tree per voxel.
            #pragma unroll
            for (int k = 0; k < 4; ++k) {
                int b0 = base[k];
                float fw = fwq[k], fh = fhq[k], fd = fdq[k];
                float v0 = tb[b0],               v1 = tb[b0 + 1];
                float v2 = tb[b0 + RWS],         v3 = tb[b0 + RWS + 1];
                float v4 = tb[b0 + DROW],        v5 = tb[b0 + DROW + 1];
                float v6 = tb[b0 + DROW + RWS];
                float v7 = tb[b0 + DROW + RWS + 1];
                float x0 = fmaf(fw, v1 - v0, v0);
                float x1 = fmaf(fw, v3 - v2, v2);
                float x2 = fmaf(fw, v5 - v4, v4);
                float x3 = fmaf(fw, v7 - v6, v6);
                float y0 = fmaf(fh, x1 - x0, x0);
                float y1 = fmaf(fh, x3 - x2, x2);
                res[k] = fmaf(fd, y1 - y0, y0);
            }
        } else {
            // Edge brick: validity folded into weights (zeros padding).
            #pragma unroll
            for (int k = 0; k < 4; ++k) {
                int d0 = (int)floorf(cdv[k]), h0 = (int)floorf(chv[k]),
                    w0 = (int)floorf(cwv[k]);
                float fd = fdq[k], fh = fhq[k], fw = fwq[k];
                float wd0 = (1.0f - fd) * ((unsigned)d0 < (unsigned)DD ? 1.0f : 0.0f);
                float wd1 = fd    * ((unsigned)(d0 + 1) < (unsigned)DD ? 1.0f : 0.0f);
                float wh0 = (1.0f - fh) * ((unsigned)h0 < (unsigned)HH ? 1.0f : 0.0f);
                float wh1 = fh    * ((unsigned)(h0 + 1) < (unsigned)HH ? 1.0f : 0.0f);
                float ww0 = (1.0f - fw) * ((unsigned)w0 < (unsigned)WW ? 1.0f : 0.0f);
                float ww1 = fw    * ((unsigned)(w0 + 1) < (unsigned)WW ? 1.0f : 0.0f);
                int b0 = base[k];
                float v0 = tb[b0],               v1 = tb[b0 + 1];
                float v2 = tb[b0 + RWS],         v3 = tb[b0 + RWS + 1];
                float v4 = tb[b0 + DROW],        v5 = tb[b0 + DROW + 1];
                float v6 = tb[b0 + DROW + RWS];
                float v7 = tb[b0 + DROW + RWS + 1];
                float a = wd0 * wh0, bq = wd0 * wh1, cq = wd1 * wh0, dq = wd1 * wh1;
                res[k] = a  * (ww0 * v0 + ww1 * v1) + bq * (ww0 * v2 + ww1 * v3) +
                         cq * (ww0 * v4 + ww1 * v5) + dq * (ww0 * v6 + ww1 * v7);
            }
        }
    } else {
        // Rare (flow beyond halo): recompute fully from global.
        #pragma unroll
        for (int k = 0; k < 4; ++k)
            res[k] = trilerp_global(sbase, cdv[k], chv[k], cwv[k]);
    }
}

__global__ __launch_bounds__(512, 4) void warp3d_kernel(
    const float* __restrict__ src, const float* __restrict__ flow,
    float* __restrict__ out) {
    __shared__ __align__(16) float tile[2][TILE_N];

    // XCD-aware swizzle: contiguous pair ranges per XCD.
    int bid = blockIdx.x;
    int wg  = (bid & 7) * CHUNK + (bid >> 3);

    int b  = wg / PAIRS_PER_B;
    int r  = wg - b * PAIRS_PER_B;
    int q  = r / (HT * WT);                // d-pair index, 0..4
    int r2 = r - q * (HT * WT);
    int ht = r2 / WT;
    int wtile = r2 - ht * WT;

    int dB0 = q * 32, hB = ht * 8, wB = wtile * 16;
    int dB4_0 = dB0 - 4, dB4_1 = dB0 + 12, hB4 = hB - 4, wB4 = wB - 4;

    bool hwok = (ht >= 1) & (ht <= HT - 2) & (wtile >= 1) & (wtile <= WT - 2);
    bool interior0 = hwok & (q >= 1);          // brick0 touches d=0 at q=0
    bool interior1 = hwok & (q <= QT - 2);     // brick1 touches d=D-1 at q=4
    bool wedge = (wtile == 0) | (wtile == WT - 1);

    const float* sbase = src + (size_t)b * DHW;

    // Output voxel mapping (wave = 4d x 4h x 16w sub-brick; 8 waves = 16x8).
    int tid  = threadIdx.x;
    int wave = tid >> 6;
    int lane = tid & 63;
    int d = dB0 + (wave >> 1) * 4 + (lane >> 4);
    int h = hB + (wave & 1) * 4 + ((lane >> 2) & 3);
    int w = wB + (lane & 3) * 4;

    size_t sOff0 = (size_t)(d * HH + h) * WW + w;
    size_t sOff1 = sOff0 + (size_t)16 * HH * WW;
    const float* fb = flow + (size_t)b * 3 * DHW;

    // Issue ALL global ops up front: flow0, flow1, stage0, stage1.
    vfloat4 fld0 = *reinterpret_cast<const vfloat4*>(fb + sOff0);
    vfloat4 flh0 = *reinterpret_cast<const vfloat4*>(fb + DHW + sOff0);
    vfloat4 flw0 = *reinterpret_cast<const vfloat4*>(fb + 2 * DHW + sOff0);
    vfloat4 fld1 = *reinterpret_cast<const vfloat4*>(fb + sOff1);
    vfloat4 flh1 = *reinterpret_cast<const vfloat4*>(fb + DHW + sOff1);
    vfloat4 flw1 = *reinterpret_cast<const vfloat4*>(fb + 2 * DHW + sOff1);

    float df0 = (float)d, df1 = (float)(d + 16);
    float hf = (float)h, wf = (float)w;

    float cdv0[4], chv0[4], cwv0[4], cdv1[4], chv1[4], cwv1[4];
    float res0[4], res1[4];

    if (!wedge) {
        // DMA staging, both bricks (5 wave-instructions each).
        #pragma unroll
        for (int bk = 0; bk < 2; ++bk) {
            int dB4x = bk ? dB4_1 : dB4_0;
            float* buf = &tile[bk][0];
            int wbase = wave * WCHUNKS;
            #pragma unroll
            for (int it = 0; it < 5; ++it) {
                int u = wbase + it * 64 + lane;
                if (u < SCHUNKS) {
                    int row = u / 6;
                    int c   = u - row * 6;
                    int ld = row >> 4, lh = row & 15;
                    int dg = min(max(dB4x + ld, 0), DD - 1);
                    int hg = min(max(hB4 + lh, 0), HH - 1);
                    const float* gsrc = sbase + (size_t)(dg * HH + hg) * WW
                                      + (wB4 + 4 * c);
                    __builtin_amdgcn_global_load_lds(
                        (const __attribute__((address_space(1))) unsigned int*)gsrc,
                        (__attribute__((address_space(3))) unsigned int*)
                            &buf[(size_t)(wbase + it * 64) * 4],
                        16, 0, 0);
                }
            }
        }

        // Coord prep brick0 (consumes flow0 -> compiler waits only flow0).
        #pragma unroll
        for (int k = 0; k < 4; ++k) {
            cdv0[k] = df0 + fld0[k];
            chv0[k] = hf + flh0[k];
            cwv0[k] = wf + (float)k + flw0[k];
        }

        // stage0 done (<=5 outstanding = stage1); stage1 stays in flight.
        asm volatile("s_waitcnt vmcnt(5)" ::: "memory");
        __builtin_amdgcn_sched_barrier(0);
        __builtin_amdgcn_s_barrier();

        compute_brick(&tile[0][0], sbase, dB4_0, hB4, wB4,
                      cdv0, chv0, cwv0, interior0, res0);
        vfloat4 o0 = {res0[0], res0[1], res0[2], res0[3]};
        *reinterpret_cast<vfloat4*>(out + (size_t)b * DHW + sOff0) = o0;

        // Coord prep brick1 overlaps compute0 scheduling.
        #pragma unroll
        for (int k = 0; k < 4; ++k) {
            cdv1[k] = df1 + fld1[k];
            chv1[k] = hf + flh1[k];
            cwv1[k] = wf + (float)k + flw1[k];
        }

        // stage1 done (allow the out-store to remain outstanding).
        asm volatile("s_waitcnt vmcnt(1)" ::: "memory");
        __builtin_amdgcn_sched_barrier(0);
        __builtin_amdgcn_s_barrier();

        compute_brick(&tile[1][0], sbase, dB4_1, hB4, wB4,
                      cdv1, chv1, cwv1, interior1, res1);
        vfloat4 o1 = {res1[0], res1[1], res1[2], res1[3]};
        *reinterpret_cast<vfloat4*>(out + (size_t)b * DHW + sOff1) = o1;
    } else {
        // w-edge pair: elementwise w-clamp register staging, conservative sync.
        #pragma unroll
        for (int bk = 0; bk < 2; ++bk) {
            int dB4x = bk ? dB4_1 : dB4_0;
            float* buf = &tile[bk][0];
            for (int u = tid; u < SCHUNKS; u += BLOCK) {
                int row = u / 6;
                int c   = u - row * 6;
                int ld = row >> 4, lh = row & 15;
                int dg = min(max(dB4x + ld, 0), DD - 1);
                int hg = min(max(hB4 + lh, 0), HH - 1);
                const float* grow = sbase + (size_t)(dg * HH + hg) * WW;
                int wg0 = wB4 + 4 * c;
                vfloat4 v;
                v.x = grow[min(max(wg0 + 0, 0), WW - 1)];
                v.y = grow[min(max(wg0 + 1, 0), WW - 1)];
                v.z = grow[min(max(wg0 + 2, 0), WW - 1)];
                v.w = grow[min(max(wg0 + 3, 0), WW - 1)];
                *reinterpret_cast<vfloat4*>(&buf[u * 4]) = v;
            }
        }
        #pragma unroll
        for (int k = 0; k < 4; ++k) {
            cdv0[k] = df0 + fld0[k];
            chv0[k] = hf + flh0[k];
            cwv0[k] = wf + (float)k + flw0[k];
            cdv1[k] = df1 + fld1[k];
            chv1[k] = hf + flh1[k];
            cwv1[k] = wf + (float)k + flw1[k];
        }
        __syncthreads();

        compute_brick(&tile[0][0], sbase, dB4_0, hB4, wB4,
                      cdv0, chv0, cwv0, interior0, res0);
        vfloat4 o0 = {res0[0], res0[1], res0[2], res0[3]};
        *reinterpret_cast<vfloat4*>(out + (size_t)b * DHW + sOff0) = o0;

        compute_brick(&tile[1][0], sbase, dB4_1, hB4, wB4,
                      cdv1, chv1, cwv1, interior1, res1);
        vfloat4 o1 = {res1[0], res1[1], res1[2], res1[3]};
        *reinterpret_cast<vfloat4*>(out + (size_t)b * DHW + sOff1) = o1;
    }
}

extern "C" void kernel_launch(void* const* d_in, const int* in_sizes, int n_in,
                              void* d_out, int out_size, void* d_ws, size_t ws_size,
                              hipStream_t stream) {
    const float* src  = (const float*)d_in[0];
    const float* flow = (const float*)d_in[1];
    float* out = (float*)d_out;

    warp3d_kernel<<<NWG, BLOCK, 0, stream>>>(src, flow, out);
}

// Round 15
// 72.990 us; speedup vs baseline: 1.1279x; 1.1279x over previous
//
#include <hip/hip_runtime.h>

// 3D trilinear warp (grid_sample, align_corners=True equivalent, zeros padding)
// src:  [B=2, C=1, D=160, H=192, W=224] f32
// flow: [B=2, 3,   D,     H,     W    ] f32  (d,h,w voxel displacements)
// out:  [B=2, C=1, D,     H,     W    ] f32
//
// R15 = R9 (best, 69.5us) with stride 24 instead of 25: rows are 96B so each
// 4-float staging chunk is 16B-aligned -> ONE ds_write_b128 per chunk
// (was 4 scalar b32; ~50% LDS-write-cycle saving). Read-side bank conflicts
// are flow-noise-randomized, not stride-systematic (R8: pad 24->25 no change;
// R13: stride-24 total conflicts 8.4M < stride-25's 9.7M).
// Structure lessons (R10-R14): 4 blocks/CU inter-block TLP is the best
// latency hider; DMA/reg-pipelining/double-buffering all regressed.

#define DD 160
#define HH 192
#define WW 224
constexpr int DHW = DD * HH * WW;          // 6,881,280
constexpr int BLOCK = 512;
// Brick: 16d x 8h x 16w.
constexpr int DT = DD / 16;                // 10
constexpr int HT = HH / 8;                 // 24
constexpr int WT = WW / 16;                // 14
constexpr int BRICKS_PER_B = DT * HT * WT; // 3360
constexpr int NWG = 2 * BRICKS_PER_B;      // 6720, divisible by 8
constexpr int NXCD = 8;
constexpr int CHUNK = NWG / NXCD;          // 840

// Staged region: halo 4 each side. d: 24; h: 16; w: 24 floats, stride 24
// (96B rows -> 16B-aligned vector staging writes).
constexpr int RD = 24, RH = 16, RWE = 24, RWS = 24;
constexpr int TILE_N = RD * RH * RWS;      // 9216 floats = 36,864 B
constexpr int SROWS = RD * RH;             // 384 staging rows
constexpr int SCHUNKS = SROWS * 6;         // 2304 float4 chunks (4.5/thread)
constexpr int DROW = RH * RWS;             // d-stride in floats (384)

typedef float vfloat4 __attribute__((ext_vector_type(4)));

// Global fallback tap (rare, beyond-halo): branchless, clamped, validity
// folded into weights — matches reference clip+valid semantics.
__device__ __forceinline__ float trilerp_global(const float* __restrict__ sbase,
                                                float cd, float ch, float cw) {
    float d0f = floorf(cd), h0f = floorf(ch), w0f = floorf(cw);
    float fd = cd - d0f, fh = ch - h0f, fw = cw - w0f;
    int d0 = (int)d0f, h0 = (int)h0f, w0 = (int)w0f;
    int d1 = d0 + 1, h1 = h0 + 1, w1 = w0 + 1;

    float wd0 = (1.0f - fd) * ((unsigned)d0 < (unsigned)DD ? 1.0f : 0.0f);
    float wd1 = fd          * ((unsigned)d1 < (unsigned)DD ? 1.0f : 0.0f);
    float wh0 = (1.0f - fh) * ((unsigned)h0 < (unsigned)HH ? 1.0f : 0.0f);
    float wh1 = fh          * ((unsigned)h1 < (unsigned)HH ? 1.0f : 0.0f);
    float ww0 = (1.0f - fw) * ((unsigned)w0 < (unsigned)WW ? 1.0f : 0.0f);
    float ww1 = fw          * ((unsigned)w1 < (unsigned)WW ? 1.0f : 0.0f);

    int d0c = min(max(d0, 0), DD - 1), d1c = min(max(d1, 0), DD - 1);
    int h0c = min(max(h0, 0), HH - 1), h1c = min(max(h1, 0), HH - 1);
    int w0c = min(max(w0, 0), WW - 1), w1c = min(max(w1, 0), WW - 1);

    const float* p00 = sbase + (d0c * HH + h0c) * WW;
    const float* p01 = sbase + (d0c * HH + h1c) * WW;
    const float* p10 = sbase + (d1c * HH + h0c) * WW;
    const float* p11 = sbase + (d1c * HH + h1c) * WW;

    return wd0 * (wh0 * (ww0 * p00[w0c] + ww1 * p00[w1c]) +
                  wh1 * (ww0 * p01[w0c] + ww1 * p01[w1c])) +
           wd1 * (wh0 * (ww0 * p10[w0c] + ww1 * p10[w1c]) +
                  wh1 * (ww0 * p11[w0c] + ww1 * p11[w1c]));
}

__global__ __launch_bounds__(512, 8) void warp3d_kernel(
    const float* __restrict__ src, const float* __restrict__ flow,
    float* __restrict__ out) {
    __shared__ __align__(16) float tile[TILE_N];

    // XCD-aware swizzle: contiguous brick ranges per XCD.
    int bid = blockIdx.x;
    int wg  = (bid & 7) * CHUNK + (bid >> 3);

    int b  = wg / BRICKS_PER_B;
    int r  = wg - b * BRICKS_PER_B;
    int dt = r / (HT * WT);
    int r2 = r - dt * (HT * WT);
    int ht = r2 / WT;
    int wtile = r2 - ht * WT;

    int dB = dt * 16, hB = ht * 8, wB = wtile * 16;
    int dB4 = dB - 4, hB4 = hB - 4, wB4 = wB - 4;

    // Region strictly inside the volume -> no validity masks needed.
    bool interior = (dt >= 1) & (dt <= DT - 2) & (ht >= 1) & (ht <= HT - 2)
                  & (wtile >= 1) & (wtile <= WT - 2);

    const float* sbase = src + (size_t)b * DHW;

    // Output voxel mapping (wave = 4d x 4h x 16w sub-brick; 8 waves = 16x8).
    int tid  = threadIdx.x;
    int wave = tid >> 6;
    int lane = tid & 63;
    int d = dB + (wave >> 1) * 4 + (lane >> 4);
    int h = hB + (wave & 1) * 4 + ((lane >> 2) & 3);
    int w = wB + (lane & 3) * 4;

    size_t sOff = (size_t)(d * HH + h) * WW + w;
    const float* fb = flow + (size_t)b * 3 * DHW + sOff;
    // Issue flow loads first; they drain while staging proceeds.
    vfloat4 fld = *reinterpret_cast<const vfloat4*>(fb);
    vfloat4 flh = *reinterpret_cast<const vfloat4*>(fb + DHW);
    vfloat4 flw = *reinterpret_cast<const vfloat4*>(fb + 2 * DHW);

    // ---- Stage src region into LDS (coalesced float4 reads, b128 writes) ----
    // 384 rows (24d x 16h) x 24 floats = 2304 float4 chunks, grid-stride.
    bool wedge = (wtile == 0) | (wtile == WT - 1);  // w-halo crosses volume
    for (int u = tid; u < SCHUNKS; u += BLOCK) {
        int row = u / 6;                   // 0..383
        int c   = u - row * 6;             // 0..5
        int ld = row >> 4, lh = row & 15;
        int dg = min(max(dB4 + ld, 0), DD - 1);
        int hg = min(max(hB4 + lh, 0), HH - 1);
        const float* grow = sbase + (size_t)(dg * HH + hg) * WW;
        int wg0 = wB4 + 4 * c;             // 16B-aligned for interior tiles
        vfloat4 v;
        if (!wedge) {
            v = *reinterpret_cast<const vfloat4*>(grow + wg0);
        } else {
            v.x = grow[min(max(wg0 + 0, 0), WW - 1)];
            v.y = grow[min(max(wg0 + 1, 0), WW - 1)];
            v.z = grow[min(max(wg0 + 2, 0), WW - 1)];
            v.w = grow[min(max(wg0 + 3, 0), WW - 1)];
        }
        // stride 24 -> chunk address u*16B is 16B-aligned: one ds_write_b128.
        *reinterpret_cast<vfloat4*>(&tile[u * 4]) = v;
    }
    __syncthreads();

    float df = (float)d, hf = (float)h, wf = (float)w;
    float fdv[4] = {fld.x, fld.y, fld.z, fld.w};
    float fhv[4] = {flh.x, flh.y, flh.z, flh.w};
    float fwv[4] = {flw.x, flw.y, flw.z, flw.w};

    float cdv[4], chv[4], cwv[4];
    float fdq[4], fhq[4], fwq[4];
    int   base[4];
    bool  okv[4];
    #pragma unroll
    for (int k = 0; k < 4; ++k) {
        float cd = df + fdv[k], ch = hf + fhv[k], cw = wf + (float)k + fwv[k];
        cdv[k] = cd; chv[k] = ch; cwv[k] = cw;
        float d0f = floorf(cd), h0f = floorf(ch), w0f = floorf(cw);
        fdq[k] = cd - d0f; fhq[k] = ch - h0f; fwq[k] = cw - w0f;
        int rd = (int)d0f - dB4, rh = (int)h0f - hB4, rw = (int)w0f - wB4;
        okv[k] = ((unsigned)rd < (unsigned)(RD - 1)) &
                 ((unsigned)rh < (unsigned)(RH - 1)) &
                 ((unsigned)rw < (unsigned)(RWE - 1));
        base[k] = (rd * RH + rh) * RWS + rw;
    }
    bool allin = okv[0] & okv[1] & okv[2] & okv[3];

    float res[4];
    if (allin) {
        if (interior) {
            // Mask-free: 8 LDS taps + 7-lerp tree per voxel.
            #pragma unroll
            for (int k = 0; k < 4; ++k) {
                int b0 = base[k];
                float fw = fwq[k], fh = fhq[k], fd = fdq[k];
                float v0 = tile[b0],                 v1 = tile[b0 + 1];
                float v2 = tile[b0 + RWS],           v3 = tile[b0 + RWS + 1];
                float v4 = tile[b0 + DROW],          v5 = tile[b0 + DROW + 1];
                float v6 = tile[b0 + DROW + RWS];
                float v7 = tile[b0 + DROW + RWS + 1];
                float x0 = fmaf(fw, v1 - v0, v0);
                float x1 = fmaf(fw, v3 - v2, v2);
                float x2 = fmaf(fw, v5 - v4, v4);
                float x3 = fmaf(fw, v7 - v6, v6);
                float y0 = fmaf(fh, x1 - x0, x0);
                float y1 = fmaf(fh, x3 - x2, x2);
                res[k] = fmaf(fd, y1 - y0, y0);
            }
        } else {
            // Edge block: validity folded into weights (zeros padding).
            #pragma unroll
            for (int k = 0; k < 4; ++k) {
                float cd = cdv[k], ch = chv[k], cw = cwv[k];
                int d0 = (int)floorf(cd), h0 = (int)floorf(ch),
                    w0 = (int)floorf(cw);
                float fd = fdq[k], fh = fhq[k], fw = fwq[k];
                float wd0 = (1.0f - fd) * ((unsigned)d0 < (unsigned)DD ? 1.0f : 0.0f);
                float wd1 = fd    * ((unsigned)(d0 + 1) < (unsigned)DD ? 1.0f : 0.0f);
                float wh0 = (1.0f - fh) * ((unsigned)h0 < (unsigned)HH ? 1.0f : 0.0f);
                float wh1 = fh    * ((unsigned)(h0 + 1) < (unsigned)HH ? 1.0f : 0.0f);
                float ww0 = (1.0f - fw) * ((unsigned)w0 < (unsigned)WW ? 1.0f : 0.0f);
                float ww1 = fw    * ((unsigned)(w0 + 1) < (unsigned)WW ? 1.0f : 0.0f);
                int b0 = base[k];
                float v0 = tile[b0],                 v1 = tile[b0 + 1];
                float v2 = tile[b0 + RWS],           v3 = tile[b0 + RWS + 1];
                float v4 = tile[b0 + DROW],          v5 = tile[b0 + DROW + 1];
                float v6 = tile[b0 + DROW + RWS];
                float v7 = tile[b0 + DROW + RWS + 1];
                float a = wd0 * wh0, bq = wd0 * wh1, cq = wd1 * wh0, dq = wd1 * wh1;
                res[k] = a  * (ww0 * v0 + ww1 * v1) + bq * (ww0 * v2 + ww1 * v3) +
                         cq * (ww0 * v4 + ww1 * v5) + dq * (ww0 * v6 + ww1 * v7);
            }
        }
    } else {
        // Rare (flow beyond halo): recompute fully from global.
        #pragma unroll
        for (int k = 0; k < 4; ++k)
            res[k] = trilerp_global(sbase, cdv[k], chv[k], cwv[k]);
    }

    vfloat4 o4 = {res[0], res[1], res[2], res[3]};
    *reinterpret_cast<vfloat4*>(out + (size_t)b * DHW + sOff) = o4;
}

extern "C" void kernel_launch(void* const* d_in, const int* in_sizes, int n_in,
                              void* d_out, int out_size, void* d_ws, size_t ws_size,
                              hipStream_t stream) {
    const float* src  = (const float*)d_in[0];
    const float* flow = (const float*)d_in[1];
    float* out = (float*)d_out;

    warp3d_kernel<<<NWG, BLOCK, 0, stream>>>(src, flow, out);
}